// Round 14
// baseline (335.873 us; speedup 1.0000x reference)
//
#include <hip/hip_runtime.h>
#include <hip/hip_bf16.h>

#define HDIM 128

typedef __bf16 bf16x8 __attribute__((ext_vector_type(8)));
typedef float f32x4 __attribute__((ext_vector_type(4)));

union Frag {
  bf16x8 v;
  uint4 u4;
  ushort u[8];
};

// ---------------------------------------------------------------------------
// prep_w: split W[k][c] fp32 into transposed bf16 hi/lo pair Wt[c][k].
// hi = bf16(w), lo = bf16(w - f32(hi)). 16384 elems -> 64 blocks.
// ---------------------------------------------------------------------------
__global__ __launch_bounds__(256) void prep_w(const float* __restrict__ W,
                                              ushort* __restrict__ hi,
                                              ushort* __restrict__ lo) {
  int i = blockIdx.x * 256 + threadIdx.x;  // i = c*128 + k
  int c = i >> 7, k = i & 127;
  float w = W[(size_t)k * HDIM + c];
  ushort h = __bfloat16_as_ushort(__float2bfloat16(w));
  float rem = w - __uint_as_float((uint32_t)h << 16);
  hi[i] = h;
  lo[i] = __bfloat16_as_ushort(__float2bfloat16(rem));
}

// ---------------------------------------------------------------------------
// gemm_mfma: out[n,128] = A[n,128] @ W (+bias), split-bf16 via MFMA.
// A fp32 split inline to (ah, al); W pre-split to Wt_hi/Wt_lo [c][k] bf16.
// acc = ah*wh + al*wh + ah*wl  (al*wl ~ 1.6e-9 rel, dropped) -> fp32 accuracy.
// Block: 256 thr = 4 waves, 16 output rows x 128 cols; wave w: cols w*32..+31
// (2 col-tiles of 16). MFMA 16x16x32_bf16: A lane=m+16*(k/8),elem=k%8;
// B lane=n+16*(k/8); D col=lane&15,row=(lane>>4)*4+reg (m89-verified).
// ---------------------------------------------------------------------------
template <bool BF16OUT, bool HAS_BIAS>
__global__ __launch_bounds__(256) void gemm_mfma(
    const float* __restrict__ A, const ushort* __restrict__ Whi,
    const ushort* __restrict__ Wlo, const float* __restrict__ bias,
    float* __restrict__ outf, __hip_bfloat16* __restrict__ outb, int n) {
  const int wave = threadIdx.x >> 6;
  const int lane = threadIdx.x & 63;
  const int l15 = lane & 15;
  const int kgrp = lane >> 4;          // 0..3
  const int row0 = blockIdx.x * 16;

  // Build A hi/lo fragments for the 4 K-blocks (all waves: same 16 rows, L1).
  int r = row0 + l15;
  bool rok = r < n;
  const float* arow = A + (size_t)(rok ? r : 0) * HDIM;
  Frag ah[4], al[4];
#pragma unroll
  for (int kb = 0; kb < 4; ++kb) {
    int k0 = kb * 32 + kgrp * 8;
    float4 v0 = *(const float4*)(arow + k0);
    float4 v1 = *(const float4*)(arow + k0 + 4);
    float vv[8] = {v0.x, v0.y, v0.z, v0.w, v1.x, v1.y, v1.z, v1.w};
#pragma unroll
    for (int j = 0; j < 8; ++j) {
      float f = rok ? vv[j] : 0.f;
      ushort h = __bfloat16_as_ushort(__float2bfloat16(f));
      float rem = f - __uint_as_float((uint32_t)h << 16);
      ah[kb].u[j] = h;
      al[kb].u[j] = __bfloat16_as_ushort(__float2bfloat16(rem));
    }
  }

#pragma unroll
  for (int t = 0; t < 2; ++t) {
    int c = wave * 32 + t * 16 + l15;   // this lane's B column / D column
    f32x4 acc = {0.f, 0.f, 0.f, 0.f};
#pragma unroll
    for (int kb = 0; kb < 4; ++kb) {
      int k0 = kb * 32 + kgrp * 8;
      Frag bh, bl;
      bh.u4 = *(const uint4*)(Whi + (size_t)c * HDIM + k0);
      bl.u4 = *(const uint4*)(Wlo + (size_t)c * HDIM + k0);
      acc = __builtin_amdgcn_mfma_f32_16x16x32_bf16(ah[kb].v, bh.v, acc, 0, 0, 0);
      acc = __builtin_amdgcn_mfma_f32_16x16x32_bf16(al[kb].v, bh.v, acc, 0, 0, 0);
      acc = __builtin_amdgcn_mfma_f32_16x16x32_bf16(ah[kb].v, bl.v, acc, 0, 0, 0);
    }
    float b = HAS_BIAS ? bias[c] : 0.f;
#pragma unroll
    for (int rg = 0; rg < 4; ++rg) {
      int rr = row0 + kgrp * 4 + rg;    // D row for this reg
      if (rr < n) {
        float o = acc[rg] + b;
        if (BF16OUT)
          outb[(size_t)rr * HDIM + c] = __float2bfloat16(o);
        else
          outf[(size_t)rr * HDIM + c] = o;
      }
    }
  }
}

// ---------------------------------------------------------------------------
// CSR build: histogram of dst, 3-kernel hierarchical exclusive scan, fill.
// ---------------------------------------------------------------------------
__global__ __launch_bounds__(256) void hist_dst(const int* __restrict__ ei,
                                                int E, int n,
                                                int* __restrict__ deg) {
  int e = blockIdx.x * 256 + threadIdx.x;
  if (e < E) {
    int s = ei[e];
    int d = ei[E + e];
    if ((unsigned)s < (unsigned)n && (unsigned)d < (unsigned)n)
      atomicAdd(&deg[d], 1);
  }
}

__global__ __launch_bounds__(1024) void scan1(const int* __restrict__ deg,
                                              int* __restrict__ partials, int n) {
  __shared__ int sm[1024];
  int i = blockIdx.x * 1024 + threadIdx.x;
  sm[threadIdx.x] = (i < n) ? deg[i] : 0;
  __syncthreads();
  for (int d = 512; d > 0; d >>= 1) {
    if (threadIdx.x < d) sm[threadIdx.x] += sm[threadIdx.x + d];
    __syncthreads();
  }
  if (threadIdx.x == 0) partials[blockIdx.x] = sm[0];
}

__global__ __launch_bounds__(1024) void scan2(int* __restrict__ partials, int G) {
  __shared__ int sm[1024];
  int tid = threadIdx.x;
  int v = (tid < G) ? partials[tid] : 0;
  sm[tid] = v;
  __syncthreads();
  for (int d = 1; d < 1024; d <<= 1) {
    int t = (tid >= d) ? sm[tid - d] : 0;
    __syncthreads();
    sm[tid] += t;
    __syncthreads();
  }
  if (tid < G) partials[tid] = sm[tid] - v;  // inclusive -> exclusive
}

__global__ __launch_bounds__(1024) void scan3(const int* __restrict__ deg,
                                              const int* __restrict__ partials,
                                              int* __restrict__ off,
                                              int* __restrict__ cur, int n) {
  __shared__ int sm[1024];
  int tid = threadIdx.x;
  int i = blockIdx.x * 1024 + tid;
  int v = (i < n) ? deg[i] : 0;
  sm[tid] = v;
  __syncthreads();
  for (int d = 1; d < 1024; d <<= 1) {
    int t = (tid >= d) ? sm[tid - d] : 0;
    __syncthreads();
    sm[tid] += t;
    __syncthreads();
  }
  if (i < n) {
    int ex = partials[blockIdx.x] + sm[tid] - v;
    off[i] = ex;
    cur[i] = ex;
    if (i == n - 1) off[n] = ex + v;
  }
}

__global__ __launch_bounds__(256) void fill_csr(const int* __restrict__ ei,
                                                int E, int n,
                                                int* __restrict__ cur,
                                                int* __restrict__ csr) {
  int e = blockIdx.x * 256 + threadIdx.x;
  if (e < E) {
    int s = ei[e];
    int d = ei[E + e];
    if ((unsigned)d < (unsigned)n && (unsigned)s < (unsigned)n) {
      int slot = atomicAdd(&cur[d], 1);
      csr[slot] = s;
    }
  }
}

// ---------------------------------------------------------------------------
// Gather core (R13-measured): SGPR-pinned csr walk, 8-wide named-reg batches.
// ---------------------------------------------------------------------------
__device__ inline float2 bf2_unpack(uint32_t u) {
  float lo = __uint_as_float(u << 16);
  float hi = __uint_as_float(u & 0xffff0000u);
  return make_float2(lo, hi);
}

__device__ inline float2 gather_sum(const uint32_t* __restrict__ Mw,
                                    const int* __restrict__ off,
                                    const int* __restrict__ csr,
                                    int node, int lane) {
  float2 acc = bf2_unpack(Mw[(size_t)node * (HDIM / 2) + lane]);  // self loop
  int s = __builtin_amdgcn_readfirstlane(off[node]);
  int e = __builtin_amdgcn_readfirstlane(off[node + 1]);
  int j = s;
  for (; j + 8 <= e; j += 8) {
    int s0 = __builtin_amdgcn_readfirstlane(csr[j + 0]);
    int s1 = __builtin_amdgcn_readfirstlane(csr[j + 1]);
    int s2 = __builtin_amdgcn_readfirstlane(csr[j + 2]);
    int s3 = __builtin_amdgcn_readfirstlane(csr[j + 3]);
    int s4 = __builtin_amdgcn_readfirstlane(csr[j + 4]);
    int s5 = __builtin_amdgcn_readfirstlane(csr[j + 5]);
    int s6 = __builtin_amdgcn_readfirstlane(csr[j + 6]);
    int s7 = __builtin_amdgcn_readfirstlane(csr[j + 7]);
    uint32_t r0 = Mw[(size_t)s0 * (HDIM / 2) + lane];
    uint32_t r1 = Mw[(size_t)s1 * (HDIM / 2) + lane];
    uint32_t r2 = Mw[(size_t)s2 * (HDIM / 2) + lane];
    uint32_t r3 = Mw[(size_t)s3 * (HDIM / 2) + lane];
    uint32_t r4 = Mw[(size_t)s4 * (HDIM / 2) + lane];
    uint32_t r5 = Mw[(size_t)s5 * (HDIM / 2) + lane];
    uint32_t r6 = Mw[(size_t)s6 * (HDIM / 2) + lane];
    uint32_t r7 = Mw[(size_t)s7 * (HDIM / 2) + lane];
    float2 v0 = bf2_unpack(r0), v1 = bf2_unpack(r1);
    float2 v2 = bf2_unpack(r2), v3 = bf2_unpack(r3);
    float2 v4 = bf2_unpack(r4), v5 = bf2_unpack(r5);
    float2 v6 = bf2_unpack(r6), v7 = bf2_unpack(r7);
    acc.x += v0.x; acc.y += v0.y;
    acc.x += v1.x; acc.y += v1.y;
    acc.x += v2.x; acc.y += v2.y;
    acc.x += v3.x; acc.y += v3.y;
    acc.x += v4.x; acc.y += v4.y;
    acc.x += v5.x; acc.y += v5.y;
    acc.x += v6.x; acc.y += v6.y;
    acc.x += v7.x; acc.y += v7.y;
  }
  for (; j + 4 <= e; j += 4) {
    int s0 = __builtin_amdgcn_readfirstlane(csr[j + 0]);
    int s1 = __builtin_amdgcn_readfirstlane(csr[j + 1]);
    int s2 = __builtin_amdgcn_readfirstlane(csr[j + 2]);
    int s3 = __builtin_amdgcn_readfirstlane(csr[j + 3]);
    uint32_t r0 = Mw[(size_t)s0 * (HDIM / 2) + lane];
    uint32_t r1 = Mw[(size_t)s1 * (HDIM / 2) + lane];
    uint32_t r2 = Mw[(size_t)s2 * (HDIM / 2) + lane];
    uint32_t r3 = Mw[(size_t)s3 * (HDIM / 2) + lane];
    float2 v0 = bf2_unpack(r0), v1 = bf2_unpack(r1);
    float2 v2 = bf2_unpack(r2), v3 = bf2_unpack(r3);
    acc.x += v0.x; acc.y += v0.y;
    acc.x += v1.x; acc.y += v1.y;
    acc.x += v2.x; acc.y += v2.y;
    acc.x += v3.x; acc.y += v3.y;
  }
  for (; j < e; ++j) {
    int s0 = __builtin_amdgcn_readfirstlane(csr[j]);
    float2 v0 = bf2_unpack(Mw[(size_t)s0 * (HDIM / 2) + lane]);
    acc.x += v0.x; acc.y += v0.y;
  }
  return acc;
}

// agg_tanh: out[v] = tanh(bias + self + neighbor sum), fp32 out.
__global__ __launch_bounds__(256) void agg_tanh(
    const __hip_bfloat16* __restrict__ M, const int* __restrict__ off,
    const int* __restrict__ csr, const float* __restrict__ bias,
    float* __restrict__ out, int n) {
  int node = (blockIdx.x * 256 + threadIdx.x) >> 6;
  int lane = threadIdx.x & 63;
  if (node >= n) return;
  int f = lane * 2;
  float2 acc = gather_sum((const uint32_t*)M, off, csr, node, lane);
  acc.x = tanhf(acc.x + bias[f]);
  acc.y = tanhf(acc.y + bias[f + 1]);
  *(float2*)(out + (size_t)node * HDIM + f) = acc;
}

// agg2_head: layer-2 aggregation fused with class_prepare + classifier.
// d_out = [n*4 logits][n*2 hp].
__global__ __launch_bounds__(256) void agg2_head(
    const __hip_bfloat16* __restrict__ M, const int* __restrict__ off,
    const int* __restrict__ csr, const float* __restrict__ b2,
    const float* __restrict__ cp_w, const float* __restrict__ cp_b,
    const float* __restrict__ cls_w, const float* __restrict__ cls_b,
    float* __restrict__ out, int n) {
  int node = (blockIdx.x * 256 + threadIdx.x) >> 6;
  int lane = threadIdx.x & 63;
  if (node >= n) return;
  int f = lane * 2;
  float2 acc = gather_sum((const uint32_t*)M, off, csr, node, lane);
  float h0 = tanhf(acc.x + b2[f]);
  float h1 = tanhf(acc.y + b2[f + 1]);
  float4 w = *(const float4*)(cp_w + lane * 4);  // rows f, f+1 of [128,2]
  float s0 = h0 * w.x + h1 * w.z;
  float s1 = h0 * w.y + h1 * w.w;
#pragma unroll
  for (int offs = 32; offs; offs >>= 1) {
    s0 += __shfl_xor(s0, offs);
    s1 += __shfl_xor(s1, offs);
  }
  if (lane == 0) {
    float p0 = tanhf(s0 + cp_b[0]);
    float p1 = tanhf(s1 + cp_b[1]);
    float4 o;
    o.x = p0 * cls_w[0] + p1 * cls_w[4] + cls_b[0];
    o.y = p0 * cls_w[1] + p1 * cls_w[5] + cls_b[1];
    o.z = p0 * cls_w[2] + p1 * cls_w[6] + cls_b[2];
    o.w = p0 * cls_w[3] + p1 * cls_w[7] + cls_b[3];
    *(float4*)(out + (size_t)node * 4) = o;
    float* hout = out + (size_t)n * 4;
    *(float2*)(hout + (size_t)node * 2) = make_float2(p0, p1);
  }
}

extern "C" void kernel_launch(void* const* d_in, const int* in_sizes, int n_in,
                              void* d_out, int out_size, void* d_ws, size_t ws_size,
                              hipStream_t stream) {
  const float* x     = (const float*)d_in[0];
  const int*   ei    = (const int*)d_in[1];
  const float* fw    = (const float*)d_in[2];
  const float* fb    = (const float*)d_in[3];
  const float* w1    = (const float*)d_in[4];
  const float* b1    = (const float*)d_in[5];
  const float* w2    = (const float*)d_in[6];
  const float* b2    = (const float*)d_in[7];
  const float* cp_w  = (const float*)d_in[8];
  const float* cp_b  = (const float*)d_in[9];
  const float* cls_w = (const float*)d_in[10];
  const float* cls_b = (const float*)d_in[11];
  float* out = (float*)d_out;

  int n = in_sizes[0] / HDIM;
  int E = in_sizes[1] / 2;
  size_t nh = (size_t)n * HDIM;
  const int WELEM = HDIM * HDIM;  // 16384

  float* A = (float*)d_ws;                         // H0 -> h1 (fp32)
  __hip_bfloat16* Mb = (__hip_bfloat16*)(A + nh);  // messages (bf16)
  int* deg = (int*)((char*)Mb + nh * sizeof(__hip_bfloat16));
  int* off = deg + n;             // n+1 entries
  int* cur = off + n + 1;
  int* csr = cur + n;             // E entries
  int* partials = csr + E;        // 1024 entries
  ushort* Wsp = (ushort*)(partials + 1024);  // 6 x 16384 bf16 splits
  ushort* Wfh = Wsp;              ushort* Wfl = Wsp + WELEM;
  ushort* W1h = Wsp + 2 * WELEM;  ushort* W1l = Wsp + 3 * WELEM;
  ushort* W2h = Wsp + 4 * WELEM;  ushort* W2l = Wsp + 5 * WELEM;

  int gemmBlocks = (n + 15) / 16;
  int edgeBlocks = (E + 255) / 256;
  int aggBlocks = (n + 3) / 4;
  int G = (n + 1023) / 1024;
  int prepBlocks = WELEM / 256;

  // W splits (hi/lo bf16, transposed to [c][k])
  prep_w<<<prepBlocks, 256, 0, stream>>>(fw, Wfh, Wfl);
  prep_w<<<prepBlocks, 256, 0, stream>>>(w1, W1h, W1l);
  prep_w<<<prepBlocks, 256, 0, stream>>>(w2, W2h, W2l);

  // CSR build (used by both layers)
  hipMemsetAsync(deg, 0, (size_t)n * sizeof(int), stream);
  hist_dst<<<edgeBlocks, 256, 0, stream>>>(ei, E, n, deg);
  scan1<<<G, 1024, 0, stream>>>(deg, partials, n);
  scan2<<<1, 1024, 0, stream>>>(partials, G);
  scan3<<<G, 1024, 0, stream>>>(deg, partials, off, cur, n);
  fill_csr<<<edgeBlocks, 256, 0, stream>>>(ei, E, n, cur, csr);

  // layer 0: A = x @ fw + fb (fp32 out, MFMA split-bf16)
  gemm_mfma<false, true><<<gemmBlocks, 256, 0, stream>>>(
      x, Wfh, Wfl, fb, A, nullptr, n);
  // layer 1: Mb = bf16(A @ w1) ; A = tanh(b1 + agg(Mb))
  gemm_mfma<true, false><<<gemmBlocks, 256, 0, stream>>>(
      A, W1h, W1l, nullptr, nullptr, Mb, n);
  agg_tanh<<<aggBlocks, 256, 0, stream>>>(Mb, off, csr, b1, A, n);
  // layer 2: Mb = bf16(A @ w2) ; fused agg + head
  gemm_mfma<true, false><<<gemmBlocks, 256, 0, stream>>>(
      A, W2h, W2l, nullptr, nullptr, Mb, n);
  agg2_head<<<aggBlocks, 256, 0, stream>>>(Mb, off, csr, b2, cp_w, cp_b,
                                           cls_w, cls_b, out, n);
}

// Round 15
// 328.272 us; speedup vs baseline: 1.0232x; 1.0232x over previous
//
#include <hip/hip_runtime.h>
#include <hip/hip_bf16.h>

#define HDIM 128

typedef __bf16 bf16x8 __attribute__((ext_vector_type(8)));
typedef float f32x4 __attribute__((ext_vector_type(4)));

union Frag {
  bf16x8 v;
  uint4 u4;
  ushort u[8];
};

// ---------------------------------------------------------------------------
// prep_w3: split all three W[k][c] fp32 matrices into transposed bf16 hi/lo
// pairs Wt[c][k], one launch. Layout in dst: [m][hi|lo][16384].
// Grid 192 blocks: m = blk>>6, chunk = (blk&63)*256.
// ---------------------------------------------------------------------------
__global__ __launch_bounds__(256) void prep_w3(const float* __restrict__ w0s,
                                               const float* __restrict__ w1s,
                                               const float* __restrict__ w2s,
                                               ushort* __restrict__ dst) {
  int m = blockIdx.x >> 6;
  int i = ((blockIdx.x & 63) << 8) + threadIdx.x;  // i = c*128 + k
  const float* W = (m == 0) ? w0s : (m == 1) ? w1s : w2s;
  int c = i >> 7, k = i & 127;
  float w = W[(size_t)k * HDIM + c];
  ushort h = __bfloat16_as_ushort(__float2bfloat16(w));
  float rem = w - __uint_as_float((uint32_t)h << 16);
  ushort* hi = dst + (size_t)m * 2 * HDIM * HDIM;
  hi[i] = h;
  hi[HDIM * HDIM + i] = __bfloat16_as_ushort(__float2bfloat16(rem));
}

// ---------------------------------------------------------------------------
// gemm_mfma: out[n,128] = A[n,128] @ W (+bias), split-bf16 via MFMA.
// R14 was latency-bound (MfmaUtil 3.8%, ILP=2 chains/wave, 4x redundant A).
// v2: 64-row block, wave w owns rows row0+w*16 (A loaded once per block),
// and computes ALL 8 col-tiles -> 8 independent accumulator chains; W loads
// for tile t+1 pipeline under tile t's MFMA; per-tile stores overlap too.
// acc = ah*wh + al*wh + ah*wl -> fp32 accuracy (verified: absmax unchanged).
// MFMA 16x16x32_bf16 layouts: A lane=m+16*(k/8),elem=k%8; B lane=n+16*(k/8);
// D col=lane&15, row=(lane>>4)*4+reg (m89-verified).
// ---------------------------------------------------------------------------
template <bool BF16OUT, bool HAS_BIAS>
__global__ __launch_bounds__(256) void gemm_mfma(
    const float* __restrict__ A, const ushort* __restrict__ Whi,
    const ushort* __restrict__ Wlo, const float* __restrict__ bias,
    float* __restrict__ outf, __hip_bfloat16* __restrict__ outb, int n) {
  const int wave = threadIdx.x >> 6;
  const int lane = threadIdx.x & 63;
  const int l15 = lane & 15;
  const int kgrp = lane >> 4;              // 0..3
  const int row0 = blockIdx.x * 64 + wave * 16;

  // A hi/lo fragments for this wave's 16 rows, 4 K-blocks.
  int r = row0 + l15;
  bool rok = r < n;
  const float* arow = A + (size_t)(rok ? r : 0) * HDIM;
  Frag ah[4], al[4];
#pragma unroll
  for (int kb = 0; kb < 4; ++kb) {
    int k0 = kb * 32 + kgrp * 8;
    float4 v0 = *(const float4*)(arow + k0);
    float4 v1 = *(const float4*)(arow + k0 + 4);
    float vv[8] = {v0.x, v0.y, v0.z, v0.w, v1.x, v1.y, v1.z, v1.w};
#pragma unroll
    for (int j = 0; j < 8; ++j) {
      float f = rok ? vv[j] : 0.f;
      ushort h = __bfloat16_as_ushort(__float2bfloat16(f));
      float rem = f - __uint_as_float((uint32_t)h << 16);
      ah[kb].u[j] = h;
      al[kb].u[j] = __bfloat16_as_ushort(__float2bfloat16(rem));
    }
  }

#pragma unroll
  for (int t = 0; t < 8; ++t) {
    int c = t * 16 + l15;                  // B column / D column
    f32x4 acc = {0.f, 0.f, 0.f, 0.f};
#pragma unroll
    for (int kb = 0; kb < 4; ++kb) {
      int k0 = kb * 32 + kgrp * 8;
      Frag bh, bl;
      bh.u4 = *(const uint4*)(Whi + (size_t)c * HDIM + k0);
      bl.u4 = *(const uint4*)(Wlo + (size_t)c * HDIM + k0);
      acc = __builtin_amdgcn_mfma_f32_16x16x32_bf16(ah[kb].v, bh.v, acc, 0, 0, 0);
      acc = __builtin_amdgcn_mfma_f32_16x16x32_bf16(al[kb].v, bh.v, acc, 0, 0, 0);
      acc = __builtin_amdgcn_mfma_f32_16x16x32_bf16(ah[kb].v, bl.v, acc, 0, 0, 0);
    }
    float b = HAS_BIAS ? bias[c] : 0.f;
#pragma unroll
    for (int rg = 0; rg < 4; ++rg) {
      int rr = row0 + kgrp * 4 + rg;       // D row for this reg
      if (rr < n) {
        float o = acc[rg] + b;
        if (BF16OUT)
          outb[(size_t)rr * HDIM + c] = __float2bfloat16(o);
        else
          outf[(size_t)rr * HDIM + c] = o;
      }
    }
  }
}

// ---------------------------------------------------------------------------
// CSR build: histogram of dst, 3-kernel hierarchical exclusive scan, fill.
// ---------------------------------------------------------------------------
__global__ __launch_bounds__(256) void hist_dst(const int* __restrict__ ei,
                                                int E, int n,
                                                int* __restrict__ deg) {
  int e = blockIdx.x * 256 + threadIdx.x;
  if (e < E) {
    int s = ei[e];
    int d = ei[E + e];
    if ((unsigned)s < (unsigned)n && (unsigned)d < (unsigned)n)
      atomicAdd(&deg[d], 1);
  }
}

__global__ __launch_bounds__(1024) void scan1(const int* __restrict__ deg,
                                              int* __restrict__ partials, int n) {
  __shared__ int sm[1024];
  int i = blockIdx.x * 1024 + threadIdx.x;
  sm[threadIdx.x] = (i < n) ? deg[i] : 0;
  __syncthreads();
  for (int d = 512; d > 0; d >>= 1) {
    if (threadIdx.x < d) sm[threadIdx.x] += sm[threadIdx.x + d];
    __syncthreads();
  }
  if (threadIdx.x == 0) partials[blockIdx.x] = sm[0];
}

__global__ __launch_bounds__(1024) void scan2(int* __restrict__ partials, int G) {
  __shared__ int sm[1024];
  int tid = threadIdx.x;
  int v = (tid < G) ? partials[tid] : 0;
  sm[tid] = v;
  __syncthreads();
  for (int d = 1; d < 1024; d <<= 1) {
    int t = (tid >= d) ? sm[tid - d] : 0;
    __syncthreads();
    sm[tid] += t;
    __syncthreads();
  }
  if (tid < G) partials[tid] = sm[tid] - v;  // inclusive -> exclusive
}

__global__ __launch_bounds__(1024) void scan3(const int* __restrict__ deg,
                                              const int* __restrict__ partials,
                                              int* __restrict__ off,
                                              int* __restrict__ cur, int n) {
  __shared__ int sm[1024];
  int tid = threadIdx.x;
  int i = blockIdx.x * 1024 + tid;
  int v = (i < n) ? deg[i] : 0;
  sm[tid] = v;
  __syncthreads();
  for (int d = 1; d < 1024; d <<= 1) {
    int t = (tid >= d) ? sm[tid - d] : 0;
    __syncthreads();
    sm[tid] += t;
    __syncthreads();
  }
  if (i < n) {
    int ex = partials[blockIdx.x] + sm[tid] - v;
    off[i] = ex;
    cur[i] = ex;
    if (i == n - 1) off[n] = ex + v;
  }
}

__global__ __launch_bounds__(256) void fill_csr(const int* __restrict__ ei,
                                                int E, int n,
                                                int* __restrict__ cur,
                                                int* __restrict__ csr) {
  int e = blockIdx.x * 256 + threadIdx.x;
  if (e < E) {
    int s = ei[e];
    int d = ei[E + e];
    if ((unsigned)d < (unsigned)n && (unsigned)s < (unsigned)n) {
      int slot = atomicAdd(&cur[d], 1);
      csr[slot] = s;
    }
  }
}

// ---------------------------------------------------------------------------
// Gather core (R13-measured): SGPR-pinned csr walk, 8-wide named-reg batches.
// ---------------------------------------------------------------------------
__device__ inline float2 bf2_unpack(uint32_t u) {
  float lo = __uint_as_float(u << 16);
  float hi = __uint_as_float(u & 0xffff0000u);
  return make_float2(lo, hi);
}

__device__ inline float2 gather_sum(const uint32_t* __restrict__ Mw,
                                    const int* __restrict__ off,
                                    const int* __restrict__ csr,
                                    int node, int lane) {
  float2 acc = bf2_unpack(Mw[(size_t)node * (HDIM / 2) + lane]);  // self loop
  int s = __builtin_amdgcn_readfirstlane(off[node]);
  int e = __builtin_amdgcn_readfirstlane(off[node + 1]);
  int j = s;
  for (; j + 8 <= e; j += 8) {
    int s0 = __builtin_amdgcn_readfirstlane(csr[j + 0]);
    int s1 = __builtin_amdgcn_readfirstlane(csr[j + 1]);
    int s2 = __builtin_amdgcn_readfirstlane(csr[j + 2]);
    int s3 = __builtin_amdgcn_readfirstlane(csr[j + 3]);
    int s4 = __builtin_amdgcn_readfirstlane(csr[j + 4]);
    int s5 = __builtin_amdgcn_readfirstlane(csr[j + 5]);
    int s6 = __builtin_amdgcn_readfirstlane(csr[j + 6]);
    int s7 = __builtin_amdgcn_readfirstlane(csr[j + 7]);
    uint32_t r0 = Mw[(size_t)s0 * (HDIM / 2) + lane];
    uint32_t r1 = Mw[(size_t)s1 * (HDIM / 2) + lane];
    uint32_t r2 = Mw[(size_t)s2 * (HDIM / 2) + lane];
    uint32_t r3 = Mw[(size_t)s3 * (HDIM / 2) + lane];
    uint32_t r4 = Mw[(size_t)s4 * (HDIM / 2) + lane];
    uint32_t r5 = Mw[(size_t)s5 * (HDIM / 2) + lane];
    uint32_t r6 = Mw[(size_t)s6 * (HDIM / 2) + lane];
    uint32_t r7 = Mw[(size_t)s7 * (HDIM / 2) + lane];
    float2 v0 = bf2_unpack(r0), v1 = bf2_unpack(r1);
    float2 v2 = bf2_unpack(r2), v3 = bf2_unpack(r3);
    float2 v4 = bf2_unpack(r4), v5 = bf2_unpack(r5);
    float2 v6 = bf2_unpack(r6), v7 = bf2_unpack(r7);
    acc.x += v0.x; acc.y += v0.y;
    acc.x += v1.x; acc.y += v1.y;
    acc.x += v2.x; acc.y += v2.y;
    acc.x += v3.x; acc.y += v3.y;
    acc.x += v4.x; acc.y += v4.y;
    acc.x += v5.x; acc.y += v5.y;
    acc.x += v6.x; acc.y += v6.y;
    acc.x += v7.x; acc.y += v7.y;
  }
  for (; j + 4 <= e; j += 4) {
    int s0 = __builtin_amdgcn_readfirstlane(csr[j + 0]);
    int s1 = __builtin_amdgcn_readfirstlane(csr[j + 1]);
    int s2 = __builtin_amdgcn_readfirstlane(csr[j + 2]);
    int s3 = __builtin_amdgcn_readfirstlane(csr[j + 3]);
    uint32_t r0 = Mw[(size_t)s0 * (HDIM / 2) + lane];
    uint32_t r1 = Mw[(size_t)s1 * (HDIM / 2) + lane];
    uint32_t r2 = Mw[(size_t)s2 * (HDIM / 2) + lane];
    uint32_t r3 = Mw[(size_t)s3 * (HDIM / 2) + lane];
    float2 v0 = bf2_unpack(r0), v1 = bf2_unpack(r1);
    float2 v2 = bf2_unpack(r2), v3 = bf2_unpack(r3);
    acc.x += v0.x; acc.y += v0.y;
    acc.x += v1.x; acc.y += v1.y;
    acc.x += v2.x; acc.y += v2.y;
    acc.x += v3.x; acc.y += v3.y;
  }
  for (; j < e; ++j) {
    int s0 = __builtin_amdgcn_readfirstlane(csr[j]);
    float2 v0 = bf2_unpack(Mw[(size_t)s0 * (HDIM / 2) + lane]);
    acc.x += v0.x; acc.y += v0.y;
  }
  return acc;
}

// agg_tanh: out[v] = tanh(bias + self + neighbor sum), fp32 out.
__global__ __launch_bounds__(256) void agg_tanh(
    const __hip_bfloat16* __restrict__ M, const int* __restrict__ off,
    const int* __restrict__ csr, const float* __restrict__ bias,
    float* __restrict__ out, int n) {
  int node = (blockIdx.x * 256 + threadIdx.x) >> 6;
  int lane = threadIdx.x & 63;
  if (node >= n) return;
  int f = lane * 2;
  float2 acc = gather_sum((const uint32_t*)M, off, csr, node, lane);
  acc.x = tanhf(acc.x + bias[f]);
  acc.y = tanhf(acc.y + bias[f + 1]);
  *(float2*)(out + (size_t)node * HDIM + f) = acc;
}

// agg2_head: layer-2 aggregation fused with class_prepare + classifier.
// d_out = [n*4 logits][n*2 hp].
__global__ __launch_bounds__(256) void agg2_head(
    const __hip_bfloat16* __restrict__ M, const int* __restrict__ off,
    const int* __restrict__ csr, const float* __restrict__ b2,
    const float* __restrict__ cp_w, const float* __restrict__ cp_b,
    const float* __restrict__ cls_w, const float* __restrict__ cls_b,
    float* __restrict__ out, int n) {
  int node = (blockIdx.x * 256 + threadIdx.x) >> 6;
  int lane = threadIdx.x & 63;
  if (node >= n) return;
  int f = lane * 2;
  float2 acc = gather_sum((const uint32_t*)M, off, csr, node, lane);
  float h0 = tanhf(acc.x + b2[f]);
  float h1 = tanhf(acc.y + b2[f + 1]);
  float4 w = *(const float4*)(cp_w + lane * 4);  // rows f, f+1 of [128,2]
  float s0 = h0 * w.x + h1 * w.z;
  float s1 = h0 * w.y + h1 * w.w;
#pragma unroll
  for (int offs = 32; offs; offs >>= 1) {
    s0 += __shfl_xor(s0, offs);
    s1 += __shfl_xor(s1, offs);
  }
  if (lane == 0) {
    float p0 = tanhf(s0 + cp_b[0]);
    float p1 = tanhf(s1 + cp_b[1]);
    float4 o;
    o.x = p0 * cls_w[0] + p1 * cls_w[4] + cls_b[0];
    o.y = p0 * cls_w[1] + p1 * cls_w[5] + cls_b[1];
    o.z = p0 * cls_w[2] + p1 * cls_w[6] + cls_b[2];
    o.w = p0 * cls_w[3] + p1 * cls_w[7] + cls_b[3];
    *(float4*)(out + (size_t)node * 4) = o;
    float* hout = out + (size_t)n * 4;
    *(float2*)(hout + (size_t)node * 2) = make_float2(p0, p1);
  }
}

extern "C" void kernel_launch(void* const* d_in, const int* in_sizes, int n_in,
                              void* d_out, int out_size, void* d_ws, size_t ws_size,
                              hipStream_t stream) {
  const float* x     = (const float*)d_in[0];
  const int*   ei    = (const int*)d_in[1];
  const float* fw    = (const float*)d_in[2];
  const float* fb    = (const float*)d_in[3];
  const float* w1    = (const float*)d_in[4];
  const float* b1    = (const float*)d_in[5];
  const float* w2    = (const float*)d_in[6];
  const float* b2    = (const float*)d_in[7];
  const float* cp_w  = (const float*)d_in[8];
  const float* cp_b  = (const float*)d_in[9];
  const float* cls_w = (const float*)d_in[10];
  const float* cls_b = (const float*)d_in[11];
  float* out = (float*)d_out;

  int n = in_sizes[0] / HDIM;
  int E = in_sizes[1] / 2;
  size_t nh = (size_t)n * HDIM;
  const int WELEM = HDIM * HDIM;  // 16384

  float* A = (float*)d_ws;                         // H0 -> h1 (fp32)
  __hip_bfloat16* Mb = (__hip_bfloat16*)(A + nh);  // messages (bf16)
  int* deg = (int*)((char*)Mb + nh * sizeof(__hip_bfloat16));
  int* off = deg + n;             // n+1 entries
  int* cur = off + n + 1;
  int* csr = cur + n;             // E entries
  int* partials = csr + E;        // 1024 entries
  ushort* Wsp = (ushort*)(partials + 1024);  // [3][hi|lo][16384] bf16 splits
  ushort* Wfh = Wsp;              ushort* Wfl = Wsp + WELEM;
  ushort* W1h = Wsp + 2 * WELEM;  ushort* W1l = Wsp + 3 * WELEM;
  ushort* W2h = Wsp + 4 * WELEM;  ushort* W2l = Wsp + 5 * WELEM;

  int gemmBlocks = (n + 63) / 64;
  int edgeBlocks = (E + 255) / 256;
  int aggBlocks = (n + 3) / 4;
  int G = (n + 1023) / 1024;

  // W splits (hi/lo bf16, transposed to [c][k]) - single launch for all 3
  prep_w3<<<192, 256, 0, stream>>>(fw, w1, w2, Wsp);

  // CSR build (used by both layers)
  hipMemsetAsync(deg, 0, (size_t)n * sizeof(int), stream);
  hist_dst<<<edgeBlocks, 256, 0, stream>>>(ei, E, n, deg);
  scan1<<<G, 1024, 0, stream>>>(deg, partials, n);
  scan2<<<1, 1024, 0, stream>>>(partials, G);
  scan3<<<G, 1024, 0, stream>>>(deg, partials, off, cur, n);
  fill_csr<<<edgeBlocks, 256, 0, stream>>>(ei, E, n, cur, csr);

  // layer 0: A = x @ fw + fb (fp32 out, MFMA split-bf16)
  gemm_mfma<false, true><<<gemmBlocks, 256, 0, stream>>>(
      x, Wfh, Wfl, fb, A, nullptr, n);
  // layer 1: Mb = bf16(A @ w1) ; A = tanh(b1 + agg(Mb))
  gemm_mfma<true, false><<<gemmBlocks, 256, 0, stream>>>(
      A, W1h, W1l, nullptr, nullptr, Mb, n);
  agg_tanh<<<aggBlocks, 256, 0, stream>>>(Mb, off, csr, b1, A, n);
  // layer 2: Mb = bf16(A @ w2) ; fused agg + head
  gemm_mfma<true, false><<<gemmBlocks, 256, 0, stream>>>(
      A, W2h, W2l, nullptr, nullptr, Mb, n);
  agg2_head<<<aggBlocks, 256, 0, stream>>>(Mb, off, csr, b2, cp_w, cp_b,
                                           cls_w, cls_b, out, n);
}

// Round 16
// 310.918 us; speedup vs baseline: 1.0803x; 1.0558x over previous
//
#include <hip/hip_runtime.h>
#include <hip/hip_bf16.h>

#define HDIM 128
#define BM 64
#define KB 16

// ---------------------------------------------------------------------------
// Tiled fp32 GEMM (R13-proven): out = A[n,128] @ W[128,128] (+bias).
// BF16OUT: epilogue converts to bf16. Optionally zeroes zbuf[0..zn) first
// (folds the deg memset into the first GEMM launch).
// ---------------------------------------------------------------------------
template <bool BF16OUT>
__global__ __launch_bounds__(256) void gemm_tiled(
    const float* __restrict__ A, const float* __restrict__ W,
    const float* __restrict__ bias, float* __restrict__ outf,
    __hip_bfloat16* __restrict__ outb, int n,
    int* __restrict__ zbuf, int zn) {
  if (zbuf) {
    for (int i = blockIdx.x * 256 + threadIdx.x; i < zn; i += gridDim.x * 256)
      zbuf[i] = 0;
  }
  __shared__ float sA[KB][BM];    // transposed: sA[k][row]
  __shared__ float sW[KB][HDIM];
  const int tid = threadIdx.x;
  const int tx = tid & 15;        // col group: cols tx*8 .. tx*8+7
  const int ty = tid >> 4;        // row group: rows ty*4 .. ty*4+3
  const int block_row = blockIdx.x * BM;

  float acc[4][8];
#pragma unroll
  for (int i = 0; i < 4; ++i)
#pragma unroll
    for (int j = 0; j < 8; ++j) acc[i][j] = 0.f;

  const int ar = tid >> 2;        // 0..63: row this thread stages
  const int ak = (tid & 3) << 2;  // 0,4,8,12: k-offset staged
  const int wk = tid >> 4;        // 0..15: W k-row staged
  const int wc = (tid & 15) << 3; // col offset staged

  for (int k0 = 0; k0 < HDIM; k0 += KB) {
    float4 av = make_float4(0.f, 0.f, 0.f, 0.f);
    int grow = block_row + ar;
    if (grow < n) av = *(const float4*)(A + (size_t)grow * HDIM + k0 + ak);
    sA[ak + 0][ar] = av.x; sA[ak + 1][ar] = av.y;
    sA[ak + 2][ar] = av.z; sA[ak + 3][ar] = av.w;

    float4 w0 = *(const float4*)(W + (size_t)(k0 + wk) * HDIM + wc);
    float4 w1 = *(const float4*)(W + (size_t)(k0 + wk) * HDIM + wc + 4);
    *(float4*)&sW[wk][wc] = w0;
    *(float4*)&sW[wk][wc + 4] = w1;
    __syncthreads();

#pragma unroll
    for (int k = 0; k < KB; ++k) {
      float4 a = *(const float4*)&sA[k][ty * 4];
      float4 wA = *(const float4*)&sW[k][tx * 8];
      float4 wB = *(const float4*)&sW[k][tx * 8 + 4];
      float av4[4] = {a.x, a.y, a.z, a.w};
      float wv[8] = {wA.x, wA.y, wA.z, wA.w, wB.x, wB.y, wB.z, wB.w};
#pragma unroll
      for (int i = 0; i < 4; ++i)
#pragma unroll
        for (int j = 0; j < 8; ++j) acc[i][j] += av4[i] * wv[j];
    }
    __syncthreads();
  }

  float bj[8];
#pragma unroll
  for (int j = 0; j < 8; ++j) bj[j] = bias ? bias[tx * 8 + j] : 0.f;
#pragma unroll
  for (int i = 0; i < 4; ++i) {
    int grow = block_row + ty * 4 + i;
    if (grow < n) {
      float o[8];
#pragma unroll
      for (int j = 0; j < 8; ++j) o[j] = acc[i][j] + bj[j];
      if (BF16OUT) {
        uint32_t pk[4];
#pragma unroll
        for (int p = 0; p < 4; ++p) {
          uint32_t lo = __bfloat16_as_ushort(__float2bfloat16(o[2 * p]));
          uint32_t hi = __bfloat16_as_ushort(__float2bfloat16(o[2 * p + 1]));
          pk[p] = lo | (hi << 16);
        }
        *(uint4*)(outb + (size_t)grow * HDIM + tx * 8) = *(uint4*)pk;
      } else {
        *(float4*)(outf + (size_t)grow * HDIM + tx * 8) = *(float4*)&o[0];
        *(float4*)(outf + (size_t)grow * HDIM + tx * 8 + 4) = *(float4*)&o[4];
      }
    }
  }
}

// ---------------------------------------------------------------------------
// CSR build: hist -> scan1 (block sums) -> scan3f (self-prefix + local scan)
// -> fill. scan2 eliminated: each scan3f block reduces partials[0..bid) itself
// (<=49 ints, trivial).
// ---------------------------------------------------------------------------
__global__ __launch_bounds__(256) void hist_dst(const int* __restrict__ ei,
                                                int E, int n,
                                                int* __restrict__ deg) {
  int e = blockIdx.x * 256 + threadIdx.x;
  if (e < E) {
    int s = ei[e];
    int d = ei[E + e];
    if ((unsigned)s < (unsigned)n && (unsigned)d < (unsigned)n)
      atomicAdd(&deg[d], 1);
  }
}

__global__ __launch_bounds__(1024) void scan1(const int* __restrict__ deg,
                                              int* __restrict__ partials, int n) {
  __shared__ int sm[1024];
  int i = blockIdx.x * 1024 + threadIdx.x;
  sm[threadIdx.x] = (i < n) ? deg[i] : 0;
  __syncthreads();
  for (int d = 512; d > 0; d >>= 1) {
    if (threadIdx.x < d) sm[threadIdx.x] += sm[threadIdx.x + d];
    __syncthreads();
  }
  if (threadIdx.x == 0) partials[blockIdx.x] = sm[0];
}

__global__ __launch_bounds__(1024) void scan3f(const int* __restrict__ deg,
                                               const int* __restrict__ partials,
                                               int* __restrict__ off,
                                               int* __restrict__ cur, int n) {
  __shared__ int sm[1024];
  int tid = threadIdx.x;
  // exclusive prefix over raw block sums partials[0..blockIdx.x)
  int pre = 0;
  for (int i = tid; i < blockIdx.x; i += 1024) pre += partials[i];
  sm[tid] = pre;
  __syncthreads();
  for (int d = 512; d > 0; d >>= 1) {
    if (tid < d) sm[tid] += sm[tid + d];
    __syncthreads();
  }
  int P = sm[0];
  __syncthreads();
  // local exclusive scan of this 1024-chunk
  int i = blockIdx.x * 1024 + tid;
  int v = (i < n) ? deg[i] : 0;
  sm[tid] = v;
  __syncthreads();
  for (int d = 1; d < 1024; d <<= 1) {
    int t = (tid >= d) ? sm[tid - d] : 0;
    __syncthreads();
    sm[tid] += t;
    __syncthreads();
  }
  if (i < n) {
    int ex = P + sm[tid] - v;
    off[i] = ex;
    cur[i] = ex;
    if (i == n - 1) off[n] = ex + v;
  }
}

__global__ __launch_bounds__(256) void fill_csr(const int* __restrict__ ei,
                                                int E, int n,
                                                int* __restrict__ cur,
                                                int* __restrict__ csr) {
  int e = blockIdx.x * 256 + threadIdx.x;
  if (e < E) {
    int s = ei[e];
    int d = ei[E + e];
    if ((unsigned)d < (unsigned)n && (unsigned)s < (unsigned)n) {
      int slot = atomicAdd(&cur[d], 1);
      csr[slot] = s;
    }
  }
}

// ---------------------------------------------------------------------------
// Gather core (R13-measured): SGPR-pinned csr walk, 8-wide named-reg batches.
// ---------------------------------------------------------------------------
__device__ inline float2 bf2_unpack(uint32_t u) {
  float lo = __uint_as_float(u << 16);
  float hi = __uint_as_float(u & 0xffff0000u);
  return make_float2(lo, hi);
}

__device__ inline float2 gather_sum(const uint32_t* __restrict__ Mw,
                                    const int* __restrict__ off,
                                    const int* __restrict__ csr,
                                    int node, int lane) {
  float2 acc = bf2_unpack(Mw[(size_t)node * (HDIM / 2) + lane]);  // self loop
  int s = __builtin_amdgcn_readfirstlane(off[node]);
  int e = __builtin_amdgcn_readfirstlane(off[node + 1]);
  int j = s;
  for (; j + 8 <= e; j += 8) {
    int s0 = __builtin_amdgcn_readfirstlane(csr[j + 0]);
    int s1 = __builtin_amdgcn_readfirstlane(csr[j + 1]);
    int s2 = __builtin_amdgcn_readfirstlane(csr[j + 2]);
    int s3 = __builtin_amdgcn_readfirstlane(csr[j + 3]);
    int s4 = __builtin_amdgcn_readfirstlane(csr[j + 4]);
    int s5 = __builtin_amdgcn_readfirstlane(csr[j + 5]);
    int s6 = __builtin_amdgcn_readfirstlane(csr[j + 6]);
    int s7 = __builtin_amdgcn_readfirstlane(csr[j + 7]);
    uint32_t r0 = Mw[(size_t)s0 * (HDIM / 2) + lane];
    uint32_t r1 = Mw[(size_t)s1 * (HDIM / 2) + lane];
    uint32_t r2 = Mw[(size_t)s2 * (HDIM / 2) + lane];
    uint32_t r3 = Mw[(size_t)s3 * (HDIM / 2) + lane];
    uint32_t r4 = Mw[(size_t)s4 * (HDIM / 2) + lane];
    uint32_t r5 = Mw[(size_t)s5 * (HDIM / 2) + lane];
    uint32_t r6 = Mw[(size_t)s6 * (HDIM / 2) + lane];
    uint32_t r7 = Mw[(size_t)s7 * (HDIM / 2) + lane];
    float2 v0 = bf2_unpack(r0), v1 = bf2_unpack(r1);
    float2 v2 = bf2_unpack(r2), v3 = bf2_unpack(r3);
    float2 v4 = bf2_unpack(r4), v5 = bf2_unpack(r5);
    float2 v6 = bf2_unpack(r6), v7 = bf2_unpack(r7);
    acc.x += v0.x; acc.y += v0.y;
    acc.x += v1.x; acc.y += v1.y;
    acc.x += v2.x; acc.y += v2.y;
    acc.x += v3.x; acc.y += v3.y;
    acc.x += v4.x; acc.y += v4.y;
    acc.x += v5.x; acc.y += v5.y;
    acc.x += v6.x; acc.y += v6.y;
    acc.x += v7.x; acc.y += v7.y;
  }
  for (; j + 4 <= e; j += 4) {
    int s0 = __builtin_amdgcn_readfirstlane(csr[j + 0]);
    int s1 = __builtin_amdgcn_readfirstlane(csr[j + 1]);
    int s2 = __builtin_amdgcn_readfirstlane(csr[j + 2]);
    int s3 = __builtin_amdgcn_readfirstlane(csr[j + 3]);
    uint32_t r0 = Mw[(size_t)s0 * (HDIM / 2) + lane];
    uint32_t r1 = Mw[(size_t)s1 * (HDIM / 2) + lane];
    uint32_t r2 = Mw[(size_t)s2 * (HDIM / 2) + lane];
    uint32_t r3 = Mw[(size_t)s3 * (HDIM / 2) + lane];
    float2 v0 = bf2_unpack(r0), v1 = bf2_unpack(r1);
    float2 v2 = bf2_unpack(r2), v3 = bf2_unpack(r3);
    acc.x += v0.x; acc.y += v0.y;
    acc.x += v1.x; acc.y += v1.y;
    acc.x += v2.x; acc.y += v2.y;
    acc.x += v3.x; acc.y += v3.y;
  }
  for (; j < e; ++j) {
    int s0 = __builtin_amdgcn_readfirstlane(csr[j]);
    float2 v0 = bf2_unpack(Mw[(size_t)s0 * (HDIM / 2) + lane]);
    acc.x += v0.x; acc.y += v0.y;
  }
  return acc;
}

// agg_tanh: out[v] = tanh(bias + self + neighbor sum), fp32 out.
__global__ __launch_bounds__(256) void agg_tanh(
    const __hip_bfloat16* __restrict__ M, const int* __restrict__ off,
    const int* __restrict__ csr, const float* __restrict__ bias,
    float* __restrict__ out, int n) {
  int node = (blockIdx.x * 256 + threadIdx.x) >> 6;
  int lane = threadIdx.x & 63;
  if (node >= n) return;
  int f = lane * 2;
  float2 acc = gather_sum((const uint32_t*)M, off, csr, node, lane);
  acc.x = tanhf(acc.x + bias[f]);
  acc.y = tanhf(acc.y + bias[f + 1]);
  *(float2*)(out + (size_t)node * HDIM + f) = acc;
}

// agg2_head: layer-2 aggregation fused with class_prepare + classifier.
// d_out = [n*4 logits][n*2 hp].
__global__ __launch_bounds__(256) void agg2_head(
    const __hip_bfloat16* __restrict__ M, const int* __restrict__ off,
    const int* __restrict__ csr, const float* __restrict__ b2,
    const float* __restrict__ cp_w, const float* __restrict__ cp_b,
    const float* __restrict__ cls_w, const float* __restrict__ cls_b,
    float* __restrict__ out, int n) {
  int node = (blockIdx.x * 256 + threadIdx.x) >> 6;
  int lane = threadIdx.x & 63;
  if (node >= n) return;
  int f = lane * 2;
  float2 acc = gather_sum((const uint32_t*)M, off, csr, node, lane);
  float h0 = tanhf(acc.x + b2[f]);
  float h1 = tanhf(acc.y + b2[f + 1]);
  float4 w = *(const float4*)(cp_w + lane * 4);  // rows f, f+1 of [128,2]
  float s0 = h0 * w.x + h1 * w.z;
  float s1 = h0 * w.y + h1 * w.w;
#pragma unroll
  for (int offs = 32; offs; offs >>= 1) {
    s0 += __shfl_xor(s0, offs);
    s1 += __shfl_xor(s1, offs);
  }
  if (lane == 0) {
    float p0 = tanhf(s0 + cp_b[0]);
    float p1 = tanhf(s1 + cp_b[1]);
    float4 o;
    o.x = p0 * cls_w[0] + p1 * cls_w[4] + cls_b[0];
    o.y = p0 * cls_w[1] + p1 * cls_w[5] + cls_b[1];
    o.z = p0 * cls_w[2] + p1 * cls_w[6] + cls_b[2];
    o.w = p0 * cls_w[3] + p1 * cls_w[7] + cls_b[3];
    *(float4*)(out + (size_t)node * 4) = o;
    float* hout = out + (size_t)n * 4;
    *(float2*)(hout + (size_t)node * 2) = make_float2(p0, p1);
  }
}

extern "C" void kernel_launch(void* const* d_in, const int* in_sizes, int n_in,
                              void* d_out, int out_size, void* d_ws, size_t ws_size,
                              hipStream_t stream) {
  const float* x     = (const float*)d_in[0];
  const int*   ei    = (const int*)d_in[1];
  const float* fw    = (const float*)d_in[2];
  const float* fb    = (const float*)d_in[3];
  const float* w1    = (const float*)d_in[4];
  const float* b1    = (const float*)d_in[5];
  const float* w2    = (const float*)d_in[6];
  const float* b2    = (const float*)d_in[7];
  const float* cp_w  = (const float*)d_in[8];
  const float* cp_b  = (const float*)d_in[9];
  const float* cls_w = (const float*)d_in[10];
  const float* cls_b = (const float*)d_in[11];
  float* out = (float*)d_out;

  int n = in_sizes[0] / HDIM;
  int E = in_sizes[1] / 2;
  size_t nh = (size_t)n * HDIM;

  float* A = (float*)d_ws;                         // H0 -> h1 (fp32)
  __hip_bfloat16* Mb = (__hip_bfloat16*)(A + nh);  // messages (bf16)
  int* deg = (int*)((char*)Mb + nh * sizeof(__hip_bfloat16));
  int* off = deg + n;             // n+1 entries
  int* cur = off + n + 1;
  int* csr = cur + n;             // E entries
  int* partials = csr + E;        // up to 1024 entries (raw block sums)

  int gemmBlocks = (n + BM - 1) / BM;
  int edgeBlocks = (E + 255) / 256;
  int aggBlocks = (n + 3) / 4;
  int G = (n + 1023) / 1024;

  // layer 0 GEMM first (independent of CSR); fuses deg-zeroing.
  gemm_tiled<false><<<gemmBlocks, 256, 0, stream>>>(x, fw, fb, A, nullptr, n,
                                                    deg, n);
  // CSR build (4 launches: hist, scan1, scan3f, fill)
  hist_dst<<<edgeBlocks, 256, 0, stream>>>(ei, E, n, deg);
  scan1<<<G, 1024, 0, stream>>>(deg, partials, n);
  scan3f<<<G, 1024, 0, stream>>>(deg, partials, off, cur, n);
  fill_csr<<<edgeBlocks, 256, 0, stream>>>(ei, E, n, cur, csr);

  // layer 1: Mb = bf16(A @ w1) ; A = tanh(b1 + agg(Mb))
  gemm_tiled<true><<<gemmBlocks, 256, 0, stream>>>(A, w1, nullptr, nullptr, Mb,
                                                   n, nullptr, 0);
  agg_tanh<<<aggBlocks, 256, 0, stream>>>(Mb, off, csr, b1, A, n);
  // layer 2: Mb = bf16(A @ w2) ; fused agg + head
  gemm_tiled<true><<<gemmBlocks, 256, 0, stream>>>(A, w2, nullptr, nullptr, Mb,
                                                   n, nullptr, 0);
  agg2_head<<<aggBlocks, 256, 0, stream>>>(Mb, off, csr, b2, cp_w, cp_b,
                                           cls_w, cls_b, out, n);
}